// Round 1
// baseline (1870.029 us; speedup 1.0000x reference)
//
#include <hip/hip_runtime.h>
#include <stdint.h>

#define BN_EPS 1e-3f

// ---- tiny: fp32 weights -> int8 sign (+1 / -1), sign(0)=+1 ----
__global__ void sign_weights(const float* __restrict__ w, int8_t* __restrict__ ws, int n) {
    int i = blockIdx.x * blockDim.x + threadIdx.x;
    if (i < n) ws[i] = (w[i] >= 0.f) ? (int8_t)1 : (int8_t)-1;
}

// ---- layer 1: conv(x fp32, sign(w1), VALID) + maxpool2 + bn + sign -> int8 ----
// x: [64,128,128,3] NHWC, w1s: [3,3,3,32] HWIO signs, out y1s: [64,63,63,32]
__global__ void conv1_pool_bnsign(const float* __restrict__ x,
                                  const int8_t* __restrict__ w1s,
                                  const float* __restrict__ m1,
                                  const float* __restrict__ v1,
                                  const float* __restrict__ b1,
                                  int8_t* __restrict__ y1s) {
    const int C = 32, P = 63;
    int idx = blockIdx.x * blockDim.x + threadIdx.x;
    int total = 64 * P * P * C;
    if (idx >= total) return;
    int c = idx & (C - 1);
    int t = idx / C;
    int pw = t % P; t /= P;
    int ph = t % P; t /= P;
    int n = t;

    float wv[27];
#pragma unroll
    for (int k = 0; k < 27; k++) wv[k] = (float)w1s[k * C + c];

    float mx = -INFINITY;
#pragma unroll
    for (int dy = 0; dy < 2; dy++) {
#pragma unroll
        for (int dx = 0; dx < 2; dx++) {
            int oh = 2 * ph + dy, ow = 2 * pw + dx;   // conv output coords (VALID)
            float acc = 0.f;
#pragma unroll
            for (int kh = 0; kh < 3; kh++) {
#pragma unroll
                for (int kw = 0; kw < 3; kw++) {
                    const float* xp = x + (((n * 128 + (oh + kh)) * 128) + (ow + kw)) * 3;
#pragma unroll
                    for (int ci = 0; ci < 3; ci++)
                        acc += xp[ci] * wv[(kh * 3 + kw) * 3 + ci];
                }
            }
            mx = fmaxf(mx, acc);
        }
    }
    float y = (mx - m1[c]) * rsqrtf(v1[c] + BN_EPS) + b1[c];
    y1s[idx] = (y >= 0.f) ? (int8_t)1 : (int8_t)-1;
}

// ---- binarized block: conv(sign in, sign w, SAME) + maxpool2 + bn (+sign) ----
// in: [64,HIN,HIN,CIN] int8 (+-1), w: [3,3,CIN,COUT] signs, out: [64,HOUT,HOUT,COUT]
template <int CIN, int COUT, int HIN, int HOUT, bool FINAL>
__global__ void bconv_pool_bn(const int8_t* __restrict__ in,
                              const int8_t* __restrict__ wsgn,
                              const float* __restrict__ m,
                              const float* __restrict__ v,
                              const float* __restrict__ b,
                              int8_t* __restrict__ outs,
                              float* __restrict__ outf) {
    int idx = blockIdx.x * blockDim.x + threadIdx.x;
    int total = 64 * HOUT * HOUT * COUT;
    if (idx >= total) return;
    int co = idx % COUT;
    int t = idx / COUT;
    int pw = t % HOUT; t /= HOUT;
    int ph = t % HOUT; t /= HOUT;
    int n = t;

    int best = -2000000000;
#pragma unroll
    for (int dy = 0; dy < 2; dy++) {
#pragma unroll
        for (int dx = 0; dx < 2; dx++) {
            int oh = 2 * ph + dy, ow = 2 * pw + dx;   // conv output coords (SAME)
            int acc = 0;
            for (int kh = 0; kh < 3; kh++) {
                int ih = oh + kh - 1;
                if (ih < 0 || ih >= HIN) continue;    // zero padding: contributes 0
                for (int kw = 0; kw < 3; kw++) {
                    int iw = ow + kw - 1;
                    if (iw < 0 || iw >= HIN) continue;
                    const int8_t* ip = in + (((n * HIN + ih) * HIN) + iw) * CIN;
                    const int8_t* wp = wsgn + ((kh * 3 + kw) * CIN) * COUT + co;
#pragma unroll 8
                    for (int ci = 0; ci < CIN; ci++)
                        acc += (int)ip[ci] * (int)wp[ci * COUT];
                }
            }
            best = max(best, acc);
        }
    }
    float y = ((float)best - m[co]) * rsqrtf(v[co] + BN_EPS) + b[co];
    if (FINAL) {
        outf[idx] = y;
    } else {
        outs[idx] = (y >= 0.f) ? (int8_t)1 : (int8_t)-1;
    }
}

extern "C" void kernel_launch(void* const* d_in, const int* in_sizes, int n_in,
                              void* d_out, int out_size, void* d_ws, size_t ws_size,
                              hipStream_t stream) {
    const float* x  = (const float*)d_in[0];
    const float* w1 = (const float*)d_in[1];
    const float* m1 = (const float*)d_in[2];
    const float* v1 = (const float*)d_in[3];
    const float* b1 = (const float*)d_in[4];
    const float* w2 = (const float*)d_in[5];
    const float* m2 = (const float*)d_in[6];
    const float* v2 = (const float*)d_in[7];
    const float* b2 = (const float*)d_in[8];
    const float* w3 = (const float*)d_in[9];
    const float* m3 = (const float*)d_in[10];
    const float* v3 = (const float*)d_in[11];
    const float* b3 = (const float*)d_in[12];
    const float* w4 = (const float*)d_in[13];
    const float* m4 = (const float*)d_in[14];
    const float* v4 = (const float*)d_in[15];
    const float* b4 = (const float*)d_in[16];
    float* out = (float*)d_out;

    char* ws = (char*)d_ws;
    size_t off = 0;
    auto take = [&](size_t bytes) -> char* {
        char* p = ws + off;
        off += (bytes + 255) & ~(size_t)255;
        return p;
    };
    int8_t* y1s = (int8_t*)take((size_t)64 * 63 * 63 * 32);
    int8_t* y2s = (int8_t*)take((size_t)64 * 31 * 31 * 64);
    int8_t* y3s = (int8_t*)take((size_t)64 * 15 * 15 * 128);
    int8_t* w1s = (int8_t*)take(3 * 3 * 3 * 32);
    int8_t* w2s = (int8_t*)take(3 * 3 * 32 * 64);
    int8_t* w3s = (int8_t*)take(3 * 3 * 64 * 128);
    int8_t* w4s = (int8_t*)take(3 * 3 * 128 * 256);

    const int TB = 256;
    sign_weights<<<(864 + TB - 1) / TB, TB, 0, stream>>>(w1, w1s, 864);
    sign_weights<<<(18432 + TB - 1) / TB, TB, 0, stream>>>(w2, w2s, 18432);
    sign_weights<<<(73728 + TB - 1) / TB, TB, 0, stream>>>(w3, w3s, 73728);
    sign_weights<<<(294912 + TB - 1) / TB, TB, 0, stream>>>(w4, w4s, 294912);

    {
        int total = 64 * 63 * 63 * 32;
        conv1_pool_bnsign<<<(total + TB - 1) / TB, TB, 0, stream>>>(x, w1s, m1, v1, b1, y1s);
    }
    {
        int total = 64 * 31 * 31 * 64;
        bconv_pool_bn<32, 64, 63, 31, false><<<(total + TB - 1) / TB, TB, 0, stream>>>(
            y1s, w2s, m2, v2, b2, y2s, nullptr);
    }
    {
        int total = 64 * 15 * 15 * 128;
        bconv_pool_bn<64, 128, 31, 15, false><<<(total + TB - 1) / TB, TB, 0, stream>>>(
            y2s, w3s, m3, v3, b3, y3s, nullptr);
    }
    {
        int total = 64 * 7 * 7 * 256;
        bconv_pool_bn<128, 256, 15, 7, true><<<(total + TB - 1) / TB, TB, 0, stream>>>(
            y3s, w4s, m4, v4, b4, nullptr, out);
    }
}

// Round 3
// 199.199 us; speedup vs baseline: 9.3877x; 9.3877x over previous
//
#include <hip/hip_runtime.h>
#include <stdint.h>

#define BN_EPS 1e-3f

// ============================================================
// Weight bit-packing: bit b of word wi (tap t, out-channel co) is 1 iff
// w[((t)*CIN + wi*32 + b)*COUT + co] < 0   (sign(0)=+1 -> bit 0)
// Layout: wp[(t*CINW + wi)*COUT + co]  (co contiguous => lane-coalesced)
// ============================================================
template <int CIN, int COUT>
__global__ void pack_w(const float* __restrict__ w, uint32_t* __restrict__ wp) {
    const int CINW = CIN / 32;
    int idx = blockIdx.x * blockDim.x + threadIdx.x;
    int total = 9 * CINW * COUT;
    if (idx >= total) return;
    int co  = idx % COUT;
    int t2  = idx / COUT;
    int wi  = t2 % CINW;
    int tap = t2 / CINW;
    uint32_t word = 0;
#pragma unroll
    for (int b = 0; b < 32; b++) {
        float val = w[((tap * CIN) + wi * 32 + b) * COUT + co];
        word |= (uint32_t)(val < 0.f) << b;
    }
    wp[idx] = word;
}

// ============================================================
// Layer 1: conv(x fp32, sign(w1), VALID 126x126) + maxpool2 + bn + sign,
// packed to one uint32 (32 channels) per pooled pixel.
// x: [64,128,128,3], w1: [3,3,3,32] fp32, y1p: [64,63,63] uint32
// One thread per pooled pixel; computes all 32 channels.
// ============================================================
__global__ void conv1_pool_bn_pack(const float* __restrict__ x,
                                   const float* __restrict__ w1,
                                   const float* __restrict__ m1,
                                   const float* __restrict__ v1,
                                   const float* __restrict__ b1,
                                   uint32_t* __restrict__ y1p) {
    __shared__ float wlds[864];  // [(kh*3+kw)*3+ci][c]
    for (int i = threadIdx.x; i < 864; i += blockDim.x)
        wlds[i] = (w1[i] >= 0.f) ? 1.f : -1.f;
    __syncthreads();

    int idx = blockIdx.x * blockDim.x + threadIdx.x;
    const int P = 63;
    int total = 64 * P * P;
    if (idx >= total) return;
    int pw = idx % P;
    int t  = idx / P;
    int ph = t % P;
    int n  = t / P;

    float mx[32];
#pragma unroll
    for (int c = 0; c < 32; c++) mx[c] = -INFINITY;

    for (int dy = 0; dy < 2; dy++) {
        for (int dx = 0; dx < 2; dx++) {
            int oh = 2 * ph + dy, ow = 2 * pw + dx;
            float acc[32];
#pragma unroll
            for (int c = 0; c < 32; c++) acc[c] = 0.f;
            for (int kh = 0; kh < 3; kh++) {
                for (int kw = 0; kw < 3; kw++) {
                    const float* xp = x + (((n * 128 + oh + kh) * 128) + (ow + kw)) * 3;
                    float x0 = xp[0], x1 = xp[1], x2 = xp[2];
                    const float* wl = wlds + ((kh * 3 + kw) * 3) * 32;
#pragma unroll
                    for (int c = 0; c < 32; c++) acc[c] += x0 * wl[c];
#pragma unroll
                    for (int c = 0; c < 32; c++) acc[c] += x1 * wl[32 + c];
#pragma unroll
                    for (int c = 0; c < 32; c++) acc[c] += x2 * wl[64 + c];
                }
            }
#pragma unroll
            for (int c = 0; c < 32; c++) mx[c] = fmaxf(mx[c], acc[c]);
        }
    }

    uint32_t word = 0;
#pragma unroll
    for (int c = 0; c < 32; c++) {
        float y = (mx[c] - m1[c]) * rsqrtf(v1[c] + BN_EPS) + b1[c];
        word |= (uint32_t)(y < 0.f) << c;
    }
    y1p[idx] = word;
}

// ============================================================
// Layer 2: bconv(SAME, 63x63, CIN=32) + maxpool2 + bn + sign -> packed
// One wave per pooled pixel; lane = co (0..63). Ballot packs 64 bits.
// y1p: [64,63,63] u32, w2p: [9][64] u32, y2p: [64,31,31] uint2
// ============================================================
__global__ void bconv2(const uint32_t* __restrict__ y1p,
                       const uint32_t* __restrict__ w2p,
                       const float* __restrict__ m, const float* __restrict__ v,
                       const float* __restrict__ b, uint2* __restrict__ y2p) {
    int wid  = (blockIdx.x * blockDim.x + threadIdx.x) >> 6;  // pixel
    int lane = threadIdx.x & 63;
    int pw = wid % 31;
    int t  = wid / 31;
    int ph = t % 31;
    int n  = t / 31;

    uint32_t wq[9];
#pragma unroll
    for (int tap = 0; tap < 9; tap++) wq[tap] = w2p[tap * 64 + lane];

    int best = -1000000;
#pragma unroll
    for (int dy = 0; dy < 2; dy++) {
#pragma unroll
        for (int dx = 0; dx < 2; dx++) {
            int oh = 2 * ph + dy, ow = 2 * pw + dx;
            int acc = 0, K = 0;
            for (int kh = 0; kh < 3; kh++) {
                int ih = oh - 1 + kh;
                if (ih < 0 || ih >= 63) continue;
                for (int kw = 0; kw < 3; kw++) {
                    int iw = ow - 1 + kw;
                    if (iw < 0 || iw >= 63) continue;
                    uint32_t iv = y1p[(n * 63 + ih) * 63 + iw];
                    acc += __popc(iv ^ wq[kh * 3 + kw]);
                    K += 32;
                }
            }
            best = max(best, K - 2 * acc);
        }
    }
    float y = ((float)best - m[lane]) * rsqrtf(v[lane] + BN_EPS) + b[lane];
    unsigned long long bal = __ballot(y < 0.f);
    if (lane == 0) y2p[wid] = make_uint2((uint32_t)bal, (uint32_t)(bal >> 32));
}

// ============================================================
// Layer 3: bconv(SAME, 31x31, CIN=64) + maxpool2 + bn + sign -> packed
// Two waves per pixel (co half). y2p: [64,31,31] uint2,
// w3p: [9][2][128] u32, y3p: [64,15,15] 4x u32
// ============================================================
__global__ void bconv3(const uint2* __restrict__ y2p,
                       const uint32_t* __restrict__ w3p,
                       const float* __restrict__ m, const float* __restrict__ v,
                       const float* __restrict__ b, uint32_t* __restrict__ y3p) {
    int gwid = (blockIdx.x * blockDim.x + threadIdx.x) >> 6;
    int lane = threadIdx.x & 63;
    int half  = gwid & 1;
    int pixel = gwid >> 1;
    int co = half * 64 + lane;
    int pw = pixel % 15;
    int t  = pixel / 15;
    int ph = t % 15;
    int n  = t / 15;

    uint32_t wq0[9], wq1[9];
#pragma unroll
    for (int tap = 0; tap < 9; tap++) {
        wq0[tap] = w3p[(tap * 2 + 0) * 128 + co];
        wq1[tap] = w3p[(tap * 2 + 1) * 128 + co];
    }

    int best = -1000000;
#pragma unroll
    for (int dy = 0; dy < 2; dy++) {
#pragma unroll
        for (int dx = 0; dx < 2; dx++) {
            int oh = 2 * ph + dy, ow = 2 * pw + dx;
            int acc = 0, K = 0;
            for (int kh = 0; kh < 3; kh++) {
                int ih = oh - 1 + kh;
                if (ih < 0 || ih >= 31) continue;
                for (int kw = 0; kw < 3; kw++) {
                    int iw = ow - 1 + kw;
                    if (iw < 0 || iw >= 31) continue;
                    uint2 iv = y2p[(n * 31 + ih) * 31 + iw];
                    int tap = kh * 3 + kw;
                    acc += __popc(iv.x ^ wq0[tap]) + __popc(iv.y ^ wq1[tap]);
                    K += 64;
                }
            }
            best = max(best, K - 2 * acc);
        }
    }
    float y = ((float)best - m[co]) * rsqrtf(v[co] + BN_EPS) + b[co];
    unsigned long long bal = __ballot(y < 0.f);
    if (lane == 0) {
        y3p[pixel * 4 + half * 2 + 0] = (uint32_t)bal;
        y3p[pixel * 4 + half * 2 + 1] = (uint32_t)(bal >> 32);
    }
}

// ============================================================
// Layer 4: bconv(SAME, 15x15, CIN=128) + maxpool2 + bn -> f32 out
// One block (256 threads) per pooled pixel; thread = co.
// y3p: [64,15,15] uint4, w4p: [9][4][256] u32, out: [64,7,7,256] f32
// ============================================================
__global__ void bconv4(const uint4* __restrict__ y3p,
                       const uint32_t* __restrict__ w4p,
                       const float* __restrict__ m, const float* __restrict__ v,
                       const float* __restrict__ b, float* __restrict__ out) {
    int pixel = blockIdx.x;
    int co = threadIdx.x;
    int pw = pixel % 7;
    int t  = pixel / 7;
    int ph = t % 7;
    int n  = t / 7;

    uint4 wq[9];
#pragma unroll
    for (int tap = 0; tap < 9; tap++) {
        wq[tap].x = w4p[(tap * 4 + 0) * 256 + co];
        wq[tap].y = w4p[(tap * 4 + 1) * 256 + co];
        wq[tap].z = w4p[(tap * 4 + 2) * 256 + co];
        wq[tap].w = w4p[(tap * 4 + 3) * 256 + co];
    }

    int best = -1000000;
#pragma unroll
    for (int dy = 0; dy < 2; dy++) {
#pragma unroll
        for (int dx = 0; dx < 2; dx++) {
            int oh = 2 * ph + dy, ow = 2 * pw + dx;
            int acc = 0, K = 0;
            for (int kh = 0; kh < 3; kh++) {
                int ih = oh - 1 + kh;
                if (ih < 0 || ih >= 15) continue;
                for (int kw = 0; kw < 3; kw++) {
                    int iw = ow - 1 + kw;
                    if (iw < 0 || iw >= 15) continue;
                    uint4 iv = y3p[(n * 15 + ih) * 15 + iw];
                    int tap = kh * 3 + kw;
                    acc += __popc(iv.x ^ wq[tap].x) + __popc(iv.y ^ wq[tap].y)
                         + __popc(iv.z ^ wq[tap].z) + __popc(iv.w ^ wq[tap].w);
                    K += 128;
                }
            }
            best = max(best, K - 2 * acc);
        }
    }
    float y = ((float)best - m[co]) * rsqrtf(v[co] + BN_EPS) + b[co];
    out[pixel * 256 + co] = y;
}

extern "C" void kernel_launch(void* const* d_in, const int* in_sizes, int n_in,
                              void* d_out, int out_size, void* d_ws, size_t ws_size,
                              hipStream_t stream) {
    const float* x  = (const float*)d_in[0];
    const float* w1 = (const float*)d_in[1];
    const float* m1 = (const float*)d_in[2];
    const float* v1 = (const float*)d_in[3];
    const float* b1 = (const float*)d_in[4];
    const float* w2 = (const float*)d_in[5];
    const float* m2 = (const float*)d_in[6];
    const float* v2 = (const float*)d_in[7];
    const float* b2 = (const float*)d_in[8];
    const float* w3 = (const float*)d_in[9];
    const float* m3 = (const float*)d_in[10];
    const float* v3 = (const float*)d_in[11];
    const float* b3 = (const float*)d_in[12];
    const float* w4 = (const float*)d_in[13];
    const float* m4 = (const float*)d_in[14];
    const float* v4 = (const float*)d_in[15];
    const float* b4 = (const float*)d_in[16];
    float* out = (float*)d_out;

    char* ws = (char*)d_ws;
    size_t off = 0;
    auto take = [&](size_t bytes) -> char* {
        char* p = ws + off;
        off += (bytes + 255) & ~(size_t)255;
        return p;
    };
    uint32_t* y1p = (uint32_t*)take((size_t)64 * 63 * 63 * 4);       // 1 word/px
    uint2*    y2p = (uint2*)take((size_t)64 * 31 * 31 * 8);          // 2 words/px
    uint32_t* y3p = (uint32_t*)take((size_t)64 * 15 * 15 * 16);      // 4 words/px
    uint32_t* w2p = (uint32_t*)take(9 * 1 * 64 * 4);
    uint32_t* w3p = (uint32_t*)take(9 * 2 * 128 * 4);
    uint32_t* w4p = (uint32_t*)take(9 * 4 * 256 * 4);

    const int TB = 256;
    pack_w<32, 64><<<(9 * 1 * 64 + TB - 1) / TB, TB, 0, stream>>>(w2, w2p);
    pack_w<64, 128><<<(9 * 2 * 128 + TB - 1) / TB, TB, 0, stream>>>(w3, w3p);
    pack_w<128, 256><<<(9 * 4 * 256 + TB - 1) / TB, TB, 0, stream>>>(w4, w4p);

    {
        int total = 64 * 63 * 63;  // pooled pixels
        conv1_pool_bn_pack<<<(total + TB - 1) / TB, TB, 0, stream>>>(
            x, w1, m1, v1, b1, y1p);
    }
    {
        int waves = 64 * 31 * 31;                   // one wave per pixel
        bconv2<<<waves / 4, TB, 0, stream>>>(y1p, w2p, m2, v2, b2, y2p);
    }
    {
        int waves = 64 * 15 * 15 * 2;               // two waves per pixel
        bconv3<<<waves / 4, TB, 0, stream>>>(y2p, w3p, m3, v3, b3, y3p);
    }
    {
        bconv4<<<64 * 7 * 7, TB, 0, stream>>>((const uint4*)y3p, w4p, m4, v4, b4, out);
    }
}

// Round 4
// 182.239 us; speedup vs baseline: 10.2614x; 1.0931x over previous
//
#include <hip/hip_runtime.h>
#include <stdint.h>

#define BN_EPS 1e-3f

// ============================================================
// Fused weight prep:
//  - w1sg: 864 floats = sign(w1) as +-1.0f (layout [tap*3+ci][32co])
//  - w2p/w3p/w4p: bit-packed signs, bit=1 <=> w<0, layout [(tap*CINW+wi)][COUT]
// ============================================================
template <int CIN, int COUT>
__device__ inline void packw(const float* __restrict__ w, uint32_t* __restrict__ wp, int idx) {
    const int CINW = CIN / 32;
    int co = idx % COUT;
    int t2 = idx / COUT;
    int wi = t2 % CINW;
    int tap = t2 / CINW;
    uint32_t word = 0;
#pragma unroll
    for (int bb = 0; bb < 32; bb++) {
        float val = w[((tap * CIN) + wi * 32 + bb) * COUT + co];
        word |= (uint32_t)(val < 0.f) << bb;
    }
    wp[idx] = word;
}

__global__ void pack_all(const float* __restrict__ w1, const float* __restrict__ w2,
                         const float* __restrict__ w3, const float* __restrict__ w4,
                         float* __restrict__ w1sg, uint32_t* __restrict__ w2p,
                         uint32_t* __restrict__ w3p, uint32_t* __restrict__ w4p) {
    int idx = blockIdx.x * 256 + threadIdx.x;
    if (idx < 864) { w1sg[idx] = (w1[idx] >= 0.f) ? 1.f : -1.f; return; }
    idx -= 864;
    if (idx < 576) { packw<32, 64>(w2, w2p, idx); return; }
    idx -= 576;
    if (idx < 2304) { packw<64, 128>(w3, w3p, idx); return; }
    idx -= 2304;
    if (idx < 9216) { packw<128, 256>(w4, w4p, idx); return; }
}

// ============================================================
// Layer 1: conv(x, sign(w1), VALID) + maxpool2 + bn + sign -> packed u32.
// Block 256 = 4 waves. Tile: 16x8 pooled pixels.
//   wave = 64 pixels x one 16-channel group (grp = wave&1, uniform per wave
//   => weights are wave-uniform scalar operands of v_fmac).
// x window (4x4x3 = 48 floats) in registers from an LDS input tile.
// ============================================================
__global__ __launch_bounds__(256) void conv1_k(const float* __restrict__ x,
                                               const float* __restrict__ wsg,
                                               const float* __restrict__ m1,
                                               const float* __restrict__ v1,
                                               const float* __restrict__ b1,
                                               uint32_t* __restrict__ y1p) {
    __shared__ float xt[18 * 102];     // 18 input rows x 34 cols x 3 ch
    __shared__ uint32_t half0[128];    // low-16-bit words per pixel

    int tile = blockIdx.x;
    int tx = tile & 3; int t2 = tile >> 2;
    int ty = t2 & 7;  int n = t2 >> 3;
    int ph0 = ty * 8, pw0 = tx * 16;
    int r0 = 2 * ph0;
    int cf0 = (2 * pw0) * 3;           // col-float origin within a 384-float row

    for (int i = threadIdx.x; i < 18 * 102; i += 256) {
        int r = i / 102, c = i % 102;
        int gr = r0 + r, gcf = cf0 + c;
        float vv = 0.f;
        if (gr < 128 && gcf < 384)
            vv = x[(size_t)(n * 128 + gr) * 384 + gcf];
        xt[i] = vv;
    }
    __syncthreads();

    int wave = threadIdx.x >> 6, lane = threadIdx.x & 63;
    int grp = wave & 1;                // channel group (uniform in wave)
    int chunk = wave >> 1;             // pixel chunk (rows 0..3 / 4..7)
    int px = lane & 15, py = (chunk << 2) + (lane >> 4);
    int ph = ph0 + py, pw = pw0 + px;

    // 4x4x3 input window in regs
    float win[48];
#pragma unroll
    for (int r = 0; r < 4; r++)
#pragma unroll
        for (int cc = 0; cc < 12; cc++)
            win[r * 12 + cc] = xt[(2 * py + r) * 102 + px * 6 + cc];

    const float* wg = wsg + grp * 16;  // uniform base
    uint32_t word = 0;
    for (int csub = 0; csub < 4; csub++) {          // 4 channels at a time
        float a[4][4];                               // [c][pos]
#pragma unroll
        for (int j = 0; j < 4; j++)
#pragma unroll
            for (int p = 0; p < 4; p++) a[j][p] = 0.f;
#pragma unroll
        for (int kh = 0; kh < 3; kh++)
#pragma unroll
            for (int kw = 0; kw < 3; kw++)
#pragma unroll
                for (int ci = 0; ci < 3; ci++) {
                    int tap = (kh * 3 + kw) * 3 + ci;
                    float x00 = win[kh * 12 + kw * 3 + ci];
                    float x01 = win[kh * 12 + (kw + 1) * 3 + ci];
                    float x10 = win[(kh + 1) * 12 + kw * 3 + ci];
                    float x11 = win[(kh + 1) * 12 + (kw + 1) * 3 + ci];
#pragma unroll
                    for (int j = 0; j < 4; j++) {
                        float w = wg[tap * 32 + csub * 4 + j];   // wave-uniform (SGPR)
                        a[j][0] += x00 * w;
                        a[j][1] += x01 * w;
                        a[j][2] += x10 * w;
                        a[j][3] += x11 * w;
                    }
                }
#pragma unroll
        for (int j = 0; j < 4; j++) {
            float mx = fmaxf(fmaxf(a[j][0], a[j][1]), fmaxf(a[j][2], a[j][3]));
            int ch = grp * 16 + csub * 4 + j;        // uniform
            float y = (mx - m1[ch]) * rsqrtf(v1[ch] + BN_EPS) + b1[ch];
            word |= (uint32_t)(y < 0.f) << (csub * 4 + j);
        }
    }

    int pix = chunk * 64 + lane;
    if (grp == 0) half0[pix] = word;
    __syncthreads();
    if (grp == 1 && ph < 63 && pw < 63)
        y1p[(n * 63 + ph) * 63 + pw] = half0[pix] | (word << 16);
}

// ============================================================
// Layer 2: bconv(SAME, 63x63, CIN=32) + maxpool2 + bn + sign -> packed
// One wave per pooled pixel; lane = co. Scalar (uniform) window loads,
// 4x4 window hoisted; fast path for interior pixels.
// ============================================================
__global__ __launch_bounds__(256) void bconv2(const uint32_t* __restrict__ y1p,
                                              const uint32_t* __restrict__ w2p,
                                              const float* __restrict__ m,
                                              const float* __restrict__ v,
                                              const float* __restrict__ b,
                                              uint2* __restrict__ y2p) {
    int wid = __builtin_amdgcn_readfirstlane(blockIdx.x * 4 + (threadIdx.x >> 6));
    int lane = threadIdx.x & 63;
    int pw = wid % 31;
    int t = wid / 31;
    int ph = t % 31;
    int n = t / 31;

    uint32_t wq[9];
#pragma unroll
    for (int tap = 0; tap < 9; tap++) wq[tap] = w2p[tap * 64 + lane];

    int best;
    if (ph > 0 && pw > 0) {            // window fully in-bounds
        const uint32_t* p = y1p + (n * 63 + (2 * ph - 1)) * 63 + (2 * pw - 1);
        uint32_t win[16];
#pragma unroll
        for (int r = 0; r < 4; r++)
#pragma unroll
            for (int c = 0; c < 4; c++)
                win[r * 4 + c] = p[r * 63 + c];
        int a0 = 0, a1 = 0, a2 = 0, a3 = 0;
#pragma unroll
        for (int kh = 0; kh < 3; kh++)
#pragma unroll
            for (int kw = 0; kw < 3; kw++) {
                uint32_t w = wq[kh * 3 + kw];
                a0 += __popc(win[kh * 4 + kw] ^ w);
                a1 += __popc(win[kh * 4 + kw + 1] ^ w);
                a2 += __popc(win[(kh + 1) * 4 + kw] ^ w);
                a3 += __popc(win[(kh + 1) * 4 + kw + 1] ^ w);
            }
        best = max(max(288 - 2 * a0, 288 - 2 * a1), max(288 - 2 * a2, 288 - 2 * a3));
    } else {
        best = -1000000;
#pragma unroll
        for (int dy = 0; dy < 2; dy++)
#pragma unroll
            for (int dx = 0; dx < 2; dx++) {
                int oh = 2 * ph + dy, ow = 2 * pw + dx;
                int acc = 0, K = 0;
                for (int kh = 0; kh < 3; kh++) {
                    int ih = oh - 1 + kh;
                    if (ih < 0 || ih >= 63) continue;
                    for (int kw = 0; kw < 3; kw++) {
                        int iw = ow - 1 + kw;
                        if (iw < 0 || iw >= 63) continue;
                        acc += __popc(y1p[(n * 63 + ih) * 63 + iw] ^ wq[kh * 3 + kw]);
                        K += 32;
                    }
                }
                best = max(best, K - 2 * acc);
            }
    }
    float y = ((float)best - m[lane]) * rsqrtf(v[lane] + BN_EPS) + b[lane];
    unsigned long long bal = __ballot(y < 0.f);
    if (lane == 0) y2p[wid] = make_uint2((uint32_t)bal, (uint32_t)(bal >> 32));
}

// ============================================================
// Layer 3: bconv(SAME, 31x31, CIN=64) + maxpool2 + bn + sign -> packed
// Wave per (pixel, co-half).
// ============================================================
__global__ __launch_bounds__(256) void bconv3(const uint2* __restrict__ y2p,
                                              const uint32_t* __restrict__ w3p,
                                              const float* __restrict__ m,
                                              const float* __restrict__ v,
                                              const float* __restrict__ b,
                                              uint32_t* __restrict__ y3p) {
    int gwid = __builtin_amdgcn_readfirstlane(blockIdx.x * 4 + (threadIdx.x >> 6));
    int lane = threadIdx.x & 63;
    int half = gwid & 1;
    int pixel = gwid >> 1;
    int co = half * 64 + lane;
    int pw = pixel % 15;
    int t = pixel / 15;
    int ph = t % 15;
    int n = t / 15;

    uint32_t wq0[9], wq1[9];
#pragma unroll
    for (int tap = 0; tap < 9; tap++) {
        wq0[tap] = w3p[(tap * 2 + 0) * 128 + co];
        wq1[tap] = w3p[(tap * 2 + 1) * 128 + co];
    }

    int best;
    if (ph > 0 && pw > 0) {
        const uint2* p = y2p + (n * 31 + (2 * ph - 1)) * 31 + (2 * pw - 1);
        uint2 win[16];
#pragma unroll
        for (int r = 0; r < 4; r++)
#pragma unroll
            for (int c = 0; c < 4; c++)
                win[r * 4 + c] = p[r * 31 + c];
        int a0 = 0, a1 = 0, a2 = 0, a3 = 0;
#pragma unroll
        for (int kh = 0; kh < 3; kh++)
#pragma unroll
            for (int kw = 0; kw < 3; kw++) {
                int tap = kh * 3 + kw;
                uint32_t u0 = wq0[tap], u1 = wq1[tap];
                a0 += __popc(win[kh * 4 + kw].x ^ u0) + __popc(win[kh * 4 + kw].y ^ u1);
                a1 += __popc(win[kh * 4 + kw + 1].x ^ u0) + __popc(win[kh * 4 + kw + 1].y ^ u1);
                a2 += __popc(win[(kh + 1) * 4 + kw].x ^ u0) + __popc(win[(kh + 1) * 4 + kw].y ^ u1);
                a3 += __popc(win[(kh + 1) * 4 + kw + 1].x ^ u0) + __popc(win[(kh + 1) * 4 + kw + 1].y ^ u1);
            }
        best = max(max(576 - 2 * a0, 576 - 2 * a1), max(576 - 2 * a2, 576 - 2 * a3));
    } else {
        best = -1000000;
#pragma unroll
        for (int dy = 0; dy < 2; dy++)
#pragma unroll
            for (int dx = 0; dx < 2; dx++) {
                int oh = 2 * ph + dy, ow = 2 * pw + dx;
                int acc = 0, K = 0;
                for (int kh = 0; kh < 3; kh++) {
                    int ih = oh - 1 + kh;
                    if (ih < 0 || ih >= 31) continue;
                    for (int kw = 0; kw < 3; kw++) {
                        int iw = ow - 1 + kw;
                        if (iw < 0 || iw >= 31) continue;
                        uint2 iv = y2p[(n * 31 + ih) * 31 + iw];
                        int tap = kh * 3 + kw;
                        acc += __popc(iv.x ^ wq0[tap]) + __popc(iv.y ^ wq1[tap]);
                        K += 64;
                    }
                }
                best = max(best, K - 2 * acc);
            }
    }
    float y = ((float)best - m[co]) * rsqrtf(v[co] + BN_EPS) + b[co];
    unsigned long long bal = __ballot(y < 0.f);
    if (lane == 0) {
        y3p[pixel * 4 + half * 2 + 0] = (uint32_t)bal;
        y3p[pixel * 4 + half * 2 + 1] = (uint32_t)(bal >> 32);
    }
}

// ============================================================
// Layer 4: bconv(SAME, 15x15, CIN=128) + maxpool2 + bn -> f32 out
// Block per pixel; wave = one co-quad (co = wave*64 + lane).
// ============================================================
__global__ __launch_bounds__(256) void bconv4(const uint4* __restrict__ y3p,
                                              const uint32_t* __restrict__ w4p,
                                              const float* __restrict__ m,
                                              const float* __restrict__ v,
                                              const float* __restrict__ b,
                                              float* __restrict__ out) {
    int pixel = blockIdx.x;
    int lane = threadIdx.x & 63;
    int co = (threadIdx.x >> 6) * 64 + lane;
    int pw = pixel % 7;
    int t = pixel / 7;
    int ph = t % 7;
    int n = t / 7;

    uint4 wq[9];
#pragma unroll
    for (int tap = 0; tap < 9; tap++) {
        wq[tap].x = w4p[(tap * 4 + 0) * 256 + co];
        wq[tap].y = w4p[(tap * 4 + 1) * 256 + co];
        wq[tap].z = w4p[(tap * 4 + 2) * 256 + co];
        wq[tap].w = w4p[(tap * 4 + 3) * 256 + co];
    }

    int best;
    if (ph > 0 && pw > 0) {
        const uint4* p = y3p + (n * 15 + (2 * ph - 1)) * 15 + (2 * pw - 1);
        int a0 = 0, a1 = 0, a2 = 0, a3 = 0;
#pragma unroll
        for (int r = 0; r < 4; r++)
#pragma unroll
            for (int c = 0; c < 4; c++) {
                uint4 iv = p[r * 15 + c];
                // contributes to positions (dy,dx) with dy in {r-2..r} cap [0,1] etc.
#pragma unroll
                for (int kh = 0; kh < 3; kh++) {
                    int dy = r - kh;
                    if (dy < 0 || dy > 1) continue;
#pragma unroll
                    for (int kw = 0; kw < 3; kw++) {
                        int dx = c - kw;
                        if (dx < 0 || dx > 1) continue;
                        int tap = kh * 3 + kw;
                        int pc = __popc(iv.x ^ wq[tap].x) + __popc(iv.y ^ wq[tap].y)
                               + __popc(iv.z ^ wq[tap].z) + __popc(iv.w ^ wq[tap].w);
                        if (dy == 0 && dx == 0) a0 += pc;
                        else if (dy == 0) a1 += pc;
                        else if (dx == 0) a2 += pc;
                        else a3 += pc;
                    }
                }
            }
        best = max(max(1152 - 2 * a0, 1152 - 2 * a1), max(1152 - 2 * a2, 1152 - 2 * a3));
    } else {
        best = -1000000;
#pragma unroll
        for (int dy = 0; dy < 2; dy++)
#pragma unroll
            for (int dx = 0; dx < 2; dx++) {
                int oh = 2 * ph + dy, ow = 2 * pw + dx;
                int acc = 0, K = 0;
                for (int kh = 0; kh < 3; kh++) {
                    int ih = oh - 1 + kh;
                    if (ih < 0 || ih >= 15) continue;
                    for (int kw = 0; kw < 3; kw++) {
                        int iw = ow - 1 + kw;
                        if (iw < 0 || iw >= 15) continue;
                        uint4 iv = y3p[(n * 15 + ih) * 15 + iw];
                        int tap = kh * 3 + kw;
                        acc += __popc(iv.x ^ wq[tap].x) + __popc(iv.y ^ wq[tap].y)
                             + __popc(iv.z ^ wq[tap].z) + __popc(iv.w ^ wq[tap].w);
                        K += 128;
                    }
                }
                best = max(best, K - 2 * acc);
            }
    }
    float y = ((float)best - m[co]) * rsqrtf(v[co] + BN_EPS) + b[co];
    out[pixel * 256 + co] = y;
}

extern "C" void kernel_launch(void* const* d_in, const int* in_sizes, int n_in,
                              void* d_out, int out_size, void* d_ws, size_t ws_size,
                              hipStream_t stream) {
    const float* x  = (const float*)d_in[0];
    const float* w1 = (const float*)d_in[1];
    const float* m1 = (const float*)d_in[2];
    const float* v1 = (const float*)d_in[3];
    const float* b1 = (const float*)d_in[4];
    const float* w2 = (const float*)d_in[5];
    const float* m2 = (const float*)d_in[6];
    const float* v2 = (const float*)d_in[7];
    const float* b2 = (const float*)d_in[8];
    const float* w3 = (const float*)d_in[9];
    const float* m3 = (const float*)d_in[10];
    const float* v3 = (const float*)d_in[11];
    const float* b3 = (const float*)d_in[12];
    const float* w4 = (const float*)d_in[13];
    const float* m4 = (const float*)d_in[14];
    const float* v4 = (const float*)d_in[15];
    const float* b4 = (const float*)d_in[16];
    float* out = (float*)d_out;

    char* ws = (char*)d_ws;
    size_t off = 0;
    auto take = [&](size_t bytes) -> char* {
        char* p = ws + off;
        off += (bytes + 255) & ~(size_t)255;
        return p;
    };
    uint32_t* y1p  = (uint32_t*)take((size_t)64 * 63 * 63 * 4);
    uint2*    y2p  = (uint2*)take((size_t)64 * 31 * 31 * 8);
    uint32_t* y3p  = (uint32_t*)take((size_t)64 * 15 * 15 * 16);
    float*    w1sg = (float*)take(864 * 4);
    uint32_t* w2p  = (uint32_t*)take(576 * 4);
    uint32_t* w3p  = (uint32_t*)take(2304 * 4);
    uint32_t* w4p  = (uint32_t*)take(9216 * 4);

    // weight prep: 864 + 576 + 2304 + 9216 = 12960 items
    pack_all<<<(12960 + 255) / 256, 256, 0, stream>>>(w1, w2, w3, w4, w1sg, w2p, w3p, w4p);

    conv1_k<<<64 * 32, 256, 0, stream>>>(x, w1sg, m1, v1, b1, y1p);

    bconv2<<<(64 * 31 * 31) / 4, 256, 0, stream>>>(y1p, w2p, m2, v2, b2, y2p);

    bconv3<<<(64 * 15 * 15 * 2) / 4, 256, 0, stream>>>(y2p, w3p, m3, v3, b3, y3p);

    bconv4<<<64 * 7 * 7, 256, 0, stream>>>((const uint4*)y3p, w4p, m4, v4, b4, out);
}

// Round 5
// 170.758 us; speedup vs baseline: 10.9514x; 1.0672x over previous
//
#include <hip/hip_runtime.h>
#include <stdint.h>

#define BN_EPS 1e-3f

// ============================================================
// Weight prep:
//  - w1m[27]: bit c = (w1[tap*32+c] < 0)   (tap = (kh*3+kw)*3+ci)
//  - w2p/w3p/w4p: bit-packed signs, bit=1 <=> w<0, layout [(tap*CINW+wi)][COUT]
// ============================================================
template <int CIN, int COUT>
__device__ inline void packw(const float* __restrict__ w, uint32_t* __restrict__ wp, int idx) {
    const int CINW = CIN / 32;
    int co = idx % COUT;
    int t2 = idx / COUT;
    int wi = t2 % CINW;
    int tap = t2 / CINW;
    uint32_t word = 0;
#pragma unroll
    for (int bb = 0; bb < 32; bb++) {
        float val = w[((tap * CIN) + wi * 32 + bb) * COUT + co];
        word |= (uint32_t)(val < 0.f) << bb;
    }
    wp[idx] = word;
}

__global__ void pack_all(const float* __restrict__ w1, const float* __restrict__ w2,
                         const float* __restrict__ w3, const float* __restrict__ w4,
                         uint32_t* __restrict__ w1m, uint32_t* __restrict__ w2p,
                         uint32_t* __restrict__ w3p, uint32_t* __restrict__ w4p) {
    int idx = blockIdx.x * 256 + threadIdx.x;
    if (idx < 27) {
        uint32_t word = 0;
#pragma unroll
        for (int c = 0; c < 32; c++)
            word |= (uint32_t)(w1[idx * 32 + c] < 0.f) << c;
        w1m[idx] = word;
        return;
    }
    idx -= 27;
    if (idx < 576) { packw<32, 64>(w2, w2p, idx); return; }
    idx -= 576;
    if (idx < 2304) { packw<64, 128>(w3, w3p, idx); return; }
    idx -= 2304;
    if (idx < 9216) { packw<128, 256>(w4, w4p, idx); return; }
}

// ============================================================
// Layer 1: conv(x, sign(w1), VALID) + maxpool2 + bn + sign -> packed u32.
// Block 256 = 4 waves, tile 16x16 pooled pixels (wave = 16x4).
// Weight signs live in SGPRs (27 mask words via readfirstlane); inner loop is
// s_cselect(+-1.0f) + v_fmac with SGPR operand. One thread = 1 pixel x 32 ch.
// ============================================================
__global__ __launch_bounds__(256) void conv1_k(const float* __restrict__ x,
                                               const uint32_t* __restrict__ w1m,
                                               const float* __restrict__ m1,
                                               const float* __restrict__ v1,
                                               const float* __restrict__ b1,
                                               uint32_t* __restrict__ y1p) {
    __shared__ float xt[34 * 104];     // 34 input rows x 102 col-floats (pad 104)

    int tile = blockIdx.x;
    int tx = tile & 3;
    int ty = (tile >> 2) & 3;
    int n  = tile >> 4;
    int ph0 = ty * 16, pw0 = tx * 16;
    int r0 = 2 * ph0;
    int cf0 = pw0 * 6;                 // col-float origin (x row = 384 floats)

    for (int i = threadIdx.x; i < 34 * 102; i += 256) {
        int r = i / 102, c = i % 102;
        int gr = r0 + r, gcf = cf0 + c;
        float vv = 0.f;
        if (gr < 128 && gcf < 384)
            vv = x[(size_t)(n * 128 + gr) * 384 + gcf];
        xt[r * 104 + c] = vv;
    }

    // masks -> SGPRs (readfirstlane guarantees scalar regs)
    uint32_t um[27];
#pragma unroll
    for (int t = 0; t < 27; t++)
        um[t] = __builtin_amdgcn_readfirstlane(w1m[t]);

    __syncthreads();

    int wave = threadIdx.x >> 6, lane = threadIdx.x & 63;
    int px = lane & 15, py = (wave << 2) + (lane >> 4);   // 0..15
    int ph = ph0 + py, pw = pw0 + px;

    // 4x4x3 input window in regs (float2 LDS reads, 8B aligned)
    float win[48];
#pragma unroll
    for (int r = 0; r < 4; r++) {
        const float2* bp = (const float2*)&xt[(2 * py + r) * 104 + 6 * px];
#pragma unroll
        for (int q = 0; q < 6; q++) {
            float2 f2 = bp[q];
            win[r * 12 + 2 * q]     = f2.x;
            win[r * 12 + 2 * q + 1] = f2.y;
        }
    }

    uint32_t word = 0;
    for (int cg = 0; cg < 8; cg++) {            // 4 channels per group
        float a[4][4];
#pragma unroll
        for (int j = 0; j < 4; j++)
#pragma unroll
            for (int p = 0; p < 4; p++) a[j][p] = 0.f;
#pragma unroll
        for (int kh = 0; kh < 3; kh++)
#pragma unroll
            for (int kw = 0; kw < 3; kw++)
#pragma unroll
                for (int ci = 0; ci < 3; ci++) {
                    int tap = (kh * 3 + kw) * 3 + ci;
                    float x00 = win[kh * 12 + kw * 3 + ci];
                    float x01 = win[kh * 12 + (kw + 1) * 3 + ci];
                    float x10 = win[(kh + 1) * 12 + kw * 3 + ci];
                    float x11 = win[(kh + 1) * 12 + (kw + 1) * 3 + ci];
                    uint32_t mw = um[tap];
#pragma unroll
                    for (int j = 0; j < 4; j++) {
                        float w = (mw & (1u << (cg * 4 + j))) ? -1.f : 1.f;  // scalar
                        a[j][0] += x00 * w;
                        a[j][1] += x01 * w;
                        a[j][2] += x10 * w;
                        a[j][3] += x11 * w;
                    }
                }
#pragma unroll
        for (int j = 0; j < 4; j++) {
            float mx = fmaxf(fmaxf(a[j][0], a[j][1]), fmaxf(a[j][2], a[j][3]));
            int ch = cg * 4 + j;
            float y = (mx - m1[ch]) * rsqrtf(v1[ch] + BN_EPS) + b1[ch];
            word |= (uint32_t)(y < 0.f) << ch;
        }
    }

    if (ph < 63 && pw < 63)
        y1p[(n * 63 + ph) * 63 + pw] = word;
}

// ============================================================
// Layer 2: bconv(SAME, 63x63, CIN=32) + maxpool2 + bn + sign -> packed
// One wave per 4-pixel row group; lane = co. Window = 4x10 uniform words
// (SGPRs). Fast path for interior groups; only top/left edges need the
// generic path (right/bottom never pad: 63 odd, pool truncates).
// ============================================================
__global__ __launch_bounds__(256) void bconv2(const uint32_t* __restrict__ y1p,
                                              const uint32_t* __restrict__ w2p,
                                              const float* __restrict__ m,
                                              const float* __restrict__ v,
                                              const float* __restrict__ b,
                                              uint2* __restrict__ y2p) {
    int gw = __builtin_amdgcn_readfirstlane(blockIdx.x * 4 + (threadIdx.x >> 6));
    int lane = threadIdx.x & 63;
    int pwg = gw & 7;          // pixel group: pw = 4*pwg + p
    int t = gw >> 3;
    int ph = t % 31;
    int n = t / 31;

    uint32_t wq[9];
#pragma unroll
    for (int tap = 0; tap < 9; tap++) wq[tap] = w2p[tap * 64 + lane];
    float mm = m[lane], vv = v[lane], bb = b[lane];

    uint2 o0, o1, o2, o3;

    if (ph > 0 && pwg > 0) {
        int row0 = 2 * ph - 1, col0 = 8 * pwg - 1;
        uint32_t win[4][10];
#pragma unroll
        for (int r = 0; r < 4; r++)
#pragma unroll
            for (int c = 0; c < 10; c++)
                win[r][c] = y1p[(n * 63 + row0 + r) * 63 + min(col0 + c, 62)];

        uint2 res[4];
#pragma unroll
        for (int p = 0; p < 4; p++) {
            int a0 = 0, a1 = 0, a2 = 0, a3 = 0;
#pragma unroll
            for (int kh = 0; kh < 3; kh++)
#pragma unroll
                for (int kw = 0; kw < 3; kw++) {
                    uint32_t w = wq[kh * 3 + kw];
                    a0 += __popc(win[kh][2 * p + kw] ^ w);
                    a1 += __popc(win[kh][2 * p + kw + 1] ^ w);
                    a2 += __popc(win[kh + 1][2 * p + kw] ^ w);
                    a3 += __popc(win[kh + 1][2 * p + kw + 1] ^ w);
                }
            int mn = min(min(a0, a1), min(a2, a3));
            int best = 288 - 2 * mn;
            float y = ((float)best - mm) * rsqrtf(vv + BN_EPS) + bb;
            unsigned long long bal = __ballot(y < 0.f);
            res[p] = make_uint2((uint32_t)bal, (uint32_t)(bal >> 32));
        }
        o0 = res[0]; o1 = res[1]; o2 = res[2]; o3 = res[3];
    } else {
        uint2 res[4];
#pragma unroll
        for (int p = 0; p < 4; p++) {
            int pw = 4 * pwg + p;
            int best = -1000000;
            if (pw < 31) {
#pragma unroll
                for (int dy = 0; dy < 2; dy++)
#pragma unroll
                    for (int dx = 0; dx < 2; dx++) {
                        int oh = 2 * ph + dy, ow = 2 * pw + dx;
                        int acc = 0, K = 0;
                        for (int kh = 0; kh < 3; kh++) {
                            int ih = oh - 1 + kh;
                            if (ih < 0 || ih >= 63) continue;
                            for (int kw = 0; kw < 3; kw++) {
                                int iw = ow - 1 + kw;
                                if (iw < 0 || iw >= 63) continue;
                                acc += __popc(y1p[(n * 63 + ih) * 63 + iw] ^ wq[kh * 3 + kw]);
                                K += 32;
                            }
                        }
                        best = max(best, K - 2 * acc);
                    }
            }
            float y = ((float)best - mm) * rsqrtf(vv + BN_EPS) + bb;
            unsigned long long bal = __ballot(y < 0.f);
            res[p] = make_uint2((uint32_t)bal, (uint32_t)(bal >> 32));
        }
        o0 = res[0]; o1 = res[1]; o2 = res[2]; o3 = res[3];
    }

    uint2 rr = o0;
    if (lane == 1) rr = o1;
    if (lane == 2) rr = o2;
    if (lane == 3) rr = o3;
    int pws = 4 * pwg + lane;
    if (lane < 4 && pws < 31)
        y2p[(n * 31 + ph) * 31 + pws] = rr;
}

// ============================================================
// Layer 3: bconv(SAME, 31x31, CIN=64) + maxpool2 + bn + sign -> packed
// Wave per (2-pixel group, co-half). Window = 4x6 uint2 uniform words.
// ============================================================
__global__ __launch_bounds__(256) void bconv3(const uint2* __restrict__ y2p,
                                              const uint32_t* __restrict__ w3p,
                                              const float* __restrict__ m,
                                              const float* __restrict__ v,
                                              const float* __restrict__ b,
                                              uint32_t* __restrict__ y3p) {
    int gw = __builtin_amdgcn_readfirstlane(blockIdx.x * 4 + (threadIdx.x >> 6));
    int lane = threadIdx.x & 63;
    int half = gw & 1;
    int t = gw >> 1;
    int pwg = t & 7;           // pw = 2*pwg + p
    t >>= 3;
    int ph = t % 15;
    int n = t / 15;
    int co = half * 64 + lane;

    uint32_t wq0[9], wq1[9];
#pragma unroll
    for (int tap = 0; tap < 9; tap++) {
        wq0[tap] = w3p[(tap * 2 + 0) * 128 + co];
        wq1[tap] = w3p[(tap * 2 + 1) * 128 + co];
    }
    float mm = m[co], vv = v[co], bb = b[co];

    unsigned long long bal0, bal1;

    if (ph > 0 && pwg > 0) {
        int row0 = 2 * ph - 1, col0 = 4 * pwg - 1;
        uint2 win[4][6];
#pragma unroll
        for (int r = 0; r < 4; r++)
#pragma unroll
            for (int c = 0; c < 6; c++)
                win[r][c] = y2p[(n * 31 + row0 + r) * 31 + min(col0 + c, 30)];

        unsigned long long bals[2];
#pragma unroll
        for (int p = 0; p < 2; p++) {
            int a0 = 0, a1 = 0, a2 = 0, a3 = 0;
#pragma unroll
            for (int kh = 0; kh < 3; kh++)
#pragma unroll
                for (int kw = 0; kw < 3; kw++) {
                    int tap = kh * 3 + kw;
                    uint32_t u0 = wq0[tap], u1 = wq1[tap];
                    a0 += __popc(win[kh][2 * p + kw].x ^ u0) + __popc(win[kh][2 * p + kw].y ^ u1);
                    a1 += __popc(win[kh][2 * p + kw + 1].x ^ u0) + __popc(win[kh][2 * p + kw + 1].y ^ u1);
                    a2 += __popc(win[kh + 1][2 * p + kw].x ^ u0) + __popc(win[kh + 1][2 * p + kw].y ^ u1);
                    a3 += __popc(win[kh + 1][2 * p + kw + 1].x ^ u0) + __popc(win[kh + 1][2 * p + kw + 1].y ^ u1);
                }
            int mn = min(min(a0, a1), min(a2, a3));
            int best = 576 - 2 * mn;
            float y = ((float)best - mm) * rsqrtf(vv + BN_EPS) + bb;
            bals[p] = __ballot(y < 0.f);
        }
        bal0 = bals[0]; bal1 = bals[1];
    } else {
        unsigned long long bals[2];
#pragma unroll
        for (int p = 0; p < 2; p++) {
            int pw = 2 * pwg + p;
            int best = -1000000;
            if (pw < 15) {
#pragma unroll
                for (int dy = 0; dy < 2; dy++)
#pragma unroll
                    for (int dx = 0; dx < 2; dx++) {
                        int oh = 2 * ph + dy, ow = 2 * pw + dx;
                        int acc = 0, K = 0;
                        for (int kh = 0; kh < 3; kh++) {
                            int ih = oh - 1 + kh;
                            if (ih < 0 || ih >= 31) continue;
                            for (int kw = 0; kw < 3; kw++) {
                                int iw = ow - 1 + kw;
                                if (iw < 0 || iw >= 31) continue;
                                uint2 iv = y2p[(n * 31 + ih) * 31 + iw];
                                int tap = kh * 3 + kw;
                                acc += __popc(iv.x ^ wq0[tap]) + __popc(iv.y ^ wq1[tap]);
                                K += 64;
                            }
                        }
                        best = max(best, K - 2 * acc);
                    }
            }
            float y = ((float)best - mm) * rsqrtf(vv + BN_EPS) + bb;
            bals[p] = __ballot(y < 0.f);
        }
        bal0 = bals[0]; bal1 = bals[1];
    }

    // lane k in 0..3 stores word k: pixel = k>>1, wordhalf = k&1
    uint32_t val = (uint32_t)bal0;
    if (lane == 1) val = (uint32_t)(bal0 >> 32);
    if (lane == 2) val = (uint32_t)bal1;
    if (lane == 3) val = (uint32_t)(bal1 >> 32);
    int p = lane >> 1;
    int pw = 2 * pwg + p;
    if (lane < 4 && pw < 15) {
        int pixel = (n * 15 + ph) * 15 + pw;
        y3p[pixel * 4 + half * 2 + (lane & 1)] = val;
    }
}

// ============================================================
// Layer 4: bconv(SAME, 15x15, CIN=128) + maxpool2 + bn -> f32 out
// Block per pixel; wave = one co-quad (co = wave*64 + lane).
// ============================================================
__global__ __launch_bounds__(256) void bconv4(const uint4* __restrict__ y3p,
                                              const uint32_t* __restrict__ w4p,
                                              const float* __restrict__ m,
                                              const float* __restrict__ v,
                                              const float* __restrict__ b,
                                              float* __restrict__ out) {
    int pixel = blockIdx.x;
    int lane = threadIdx.x & 63;
    int co = (threadIdx.x >> 6) * 64 + lane;
    int pw = pixel % 7;
    int t = pixel / 7;
    int ph = t % 7;
    int n = t / 7;

    uint4 wq[9];
#pragma unroll
    for (int tap = 0; tap < 9; tap++) {
        wq[tap].x = w4p[(tap * 4 + 0) * 256 + co];
        wq[tap].y = w4p[(tap * 4 + 1) * 256 + co];
        wq[tap].z = w4p[(tap * 4 + 2) * 256 + co];
        wq[tap].w = w4p[(tap * 4 + 3) * 256 + co];
    }

    int best;
    if (ph > 0 && pw > 0) {
        const uint4* p = y3p + (n * 15 + (2 * ph - 1)) * 15 + (2 * pw - 1);
        int a0 = 0, a1 = 0, a2 = 0, a3 = 0;
#pragma unroll
        for (int r = 0; r < 4; r++)
#pragma unroll
            for (int c = 0; c < 4; c++) {
                uint4 iv = p[r * 15 + c];
#pragma unroll
                for (int kh = 0; kh < 3; kh++) {
                    int dy = r - kh;
                    if (dy < 0 || dy > 1) continue;
#pragma unroll
                    for (int kw = 0; kw < 3; kw++) {
                        int dx = c - kw;
                        if (dx < 0 || dx > 1) continue;
                        int tap = kh * 3 + kw;
                        int pc = __popc(iv.x ^ wq[tap].x) + __popc(iv.y ^ wq[tap].y)
                               + __popc(iv.z ^ wq[tap].z) + __popc(iv.w ^ wq[tap].w);
                        if (dy == 0 && dx == 0) a0 += pc;
                        else if (dy == 0) a1 += pc;
                        else if (dx == 0) a2 += pc;
                        else a3 += pc;
                    }
                }
            }
        best = max(max(1152 - 2 * a0, 1152 - 2 * a1), max(1152 - 2 * a2, 1152 - 2 * a3));
    } else {
        best = -1000000;
#pragma unroll
        for (int dy = 0; dy < 2; dy++)
#pragma unroll
            for (int dx = 0; dx < 2; dx++) {
                int oh = 2 * ph + dy, ow = 2 * pw + dx;
                int acc = 0, K = 0;
                for (int kh = 0; kh < 3; kh++) {
                    int ih = oh - 1 + kh;
                    if (ih < 0 || ih >= 15) continue;
                    for (int kw = 0; kw < 3; kw++) {
                        int iw = ow - 1 + kw;
                        if (iw < 0 || iw >= 15) continue;
                        uint4 iv = y3p[(n * 15 + ih) * 15 + iw];
                        int tap = kh * 3 + kw;
                        acc += __popc(iv.x ^ wq[tap].x) + __popc(iv.y ^ wq[tap].y)
                             + __popc(iv.z ^ wq[tap].z) + __popc(iv.w ^ wq[tap].w);
                        K += 128;
                    }
                }
                best = max(best, K - 2 * acc);
            }
    }
    float y = ((float)best - m[co]) * rsqrtf(v[co] + BN_EPS) + b[co];
    out[pixel * 256 + co] = y;
}

extern "C" void kernel_launch(void* const* d_in, const int* in_sizes, int n_in,
                              void* d_out, int out_size, void* d_ws, size_t ws_size,
                              hipStream_t stream) {
    const float* x  = (const float*)d_in[0];
    const float* w1 = (const float*)d_in[1];
    const float* m1 = (const float*)d_in[2];
    const float* v1 = (const float*)d_in[3];
    const float* b1 = (const float*)d_in[4];
    const float* w2 = (const float*)d_in[5];
    const float* m2 = (const float*)d_in[6];
    const float* v2 = (const float*)d_in[7];
    const float* b2 = (const float*)d_in[8];
    const float* w3 = (const float*)d_in[9];
    const float* m3 = (const float*)d_in[10];
    const float* v3 = (const float*)d_in[11];
    const float* b3 = (const float*)d_in[12];
    const float* w4 = (const float*)d_in[13];
    const float* m4 = (const float*)d_in[14];
    const float* v4 = (const float*)d_in[15];
    const float* b4 = (const float*)d_in[16];
    float* out = (float*)d_out;

    char* ws = (char*)d_ws;
    size_t off = 0;
    auto take = [&](size_t bytes) -> char* {
        char* p = ws + off;
        off += (bytes + 255) & ~(size_t)255;
        return p;
    };
    uint32_t* y1p = (uint32_t*)take((size_t)64 * 63 * 63 * 4);
    uint2*    y2p = (uint2*)take((size_t)64 * 31 * 31 * 8);
    uint32_t* y3p = (uint32_t*)take((size_t)64 * 15 * 15 * 16);
    uint32_t* w1m = (uint32_t*)take(27 * 4);
    uint32_t* w2p = (uint32_t*)take(576 * 4);
    uint32_t* w3p = (uint32_t*)take(2304 * 4);
    uint32_t* w4p = (uint32_t*)take(9216 * 4);

    // weight prep: 27 + 576 + 2304 + 9216 = 12123 items
    pack_all<<<(12123 + 255) / 256, 256, 0, stream>>>(w1, w2, w3, w4, w1m, w2p, w3p, w4p);

    conv1_k<<<64 * 16, 256, 0, stream>>>(x, w1m, m1, v1, b1, y1p);

    bconv2<<<(64 * 31 * 8) / 4, 256, 0, stream>>>(y1p, w2p, m2, v2, b2, y2p);

    bconv3<<<(64 * 15 * 8 * 2) / 4, 256, 0, stream>>>(y2p, w3p, m3, v3, b3, y3p);

    bconv4<<<64 * 7 * 7, 256, 0, stream>>>((const uint4*)y3p, w4p, m4, v4, b4, out);
}